// Round 7
// baseline (213.317 us; speedup 1.0000x reference)
//
#include <hip/hip_runtime.h>
#include <hip/hip_bf16.h>

// FeaStNet NeighbourAssignment — 3 launches:
//   k1_pre : ST[i][0:8]=s_i, ST[i][8:16]=exp(t_i) ; xbf=bf16(x) ;
//            WtB=bf16(Wcat^T) ; rowptr from sorted dst
//   k3_fused: per node i (one wave): 8-edge batches, inline softmax
//            q[e][m] = u_m*et[src][m] / sum_m (u=e^s wave-resident),
//            q broadcast via v_readlane (no LDS), G accum in regs -> Gbf
//   k4_mfma: out = (Gbf @ Wcat + R @ b)/8 via bf16 MFMA, W read from L2

#define CDIM 64
#define SDIM 8

typedef __bf16 bf16x8 __attribute__((ext_vector_type(8)));
typedef float f32x4 __attribute__((ext_vector_type(4)));

__device__ __forceinline__ float rdlane(float v, int l) {
  return __int_as_float(__builtin_amdgcn_readlane(__float_as_int(v), l));
}

// blocks [0,nb1): ST + xbf ; [nb1,nb1+128): WtB ; [nb1+128, +nbE): rowptr
__global__ __launch_bounds__(256) void k1_pre(
    const float* __restrict__ x, const float* __restrict__ Ws,
    const float* __restrict__ bs, const float* __restrict__ Wt,
    const float* __restrict__ bt, const float* __restrict__ W,
    const int* __restrict__ dst, float* __restrict__ ST,
    __hip_bfloat16* __restrict__ xbf, __hip_bfloat16* __restrict__ WtB,
    int* __restrict__ rowptr, int N, int E, int nb1) {
  int bid = blockIdx.x;
  if (bid >= nb1 + 128) {  // rowptr build (dst sorted)
    int e = (bid - nb1 - 128) * 256 + threadIdx.x;
    if (e >= E) return;
    int a = dst[e];
    int bnd = (e + 1 < E) ? dst[e + 1] : N;
    if (e == 0) {
      for (int d = 0; d <= a; ++d) rowptr[d] = 0;
    }
    for (int d = a + 1; d <= bnd; ++d) rowptr[d] = e + 1;
    return;
  }
  if (bid >= nb1) {  // Wcat[512][64] -> WtB[64][512] bf16
    int t = (bid - nb1) * 256 + threadIdx.x;  // 0..32767
    int o = t >> 9, k = t & 511;
    WtB[t] = __float2bfloat16(W[(size_t)k * 64 + o]);
    return;
  }
  int tid = bid * 256 + threadIdx.x;
  int i = tid >> 4, m = tid & 15;
  if (i >= N) return;
  int mm = m & 7;
  const float* Wp = (m < 8) ? Ws : Wt;
  float acc = (m < 8) ? bs[mm] : bt[mm];
  const float* xr = x + (size_t)i * CDIM;
#pragma unroll
  for (int c = 0; c < CDIM; ++c) acc += xr[c] * Wp[c * SDIM + mm];
  // t-part stored as exp(t): |s+t| <= ~12 in practice, e^z fp32-safe
  ST[i * 16 + m] = (m < 8) ? acc : __expf(acc);
  float4 xv4 = *(const float4*)(xr + m * 4);
  union { __hip_bfloat16 h[4]; ushort4 u; } cv;
  cv.h[0] = __float2bfloat16(xv4.x);
  cv.h[1] = __float2bfloat16(xv4.y);
  cv.h[2] = __float2bfloat16(xv4.z);
  cv.h[3] = __float2bfloat16(xv4.w);
  *(ushort4*)(xbf + (size_t)i * CDIM + m * 4) = cv.u;
}

// One wave per node. 8-edge batches; lane -> (kk=lane>>3, mm=lane&7).
__global__ __launch_bounds__(256) void k3_fused(
    const __hip_bfloat16* __restrict__ xbf, const int* __restrict__ src,
    const int* __restrict__ rowptr, const float* __restrict__ ST,
    __hip_bfloat16* __restrict__ Gbf, float* __restrict__ R, int N) {
  int wave = __builtin_amdgcn_readfirstlane(threadIdx.x >> 6);
  int lane = threadIdx.x & 63;
  int i = blockIdx.x * 4 + wave;
  if (i >= N) return;

  int lo = rowptr[i];
  int hi = rowptr[i + 1];
  int mm = lane & 7;
  int kk = lane >> 3;

  float uv = __expf(ST[i * 16 + mm]);  // e^{s_m}, wave-resident

  float g[8] = {0, 0, 0, 0, 0, 0, 0, 0};
  float racc = 0.f;

  if (lo < hi) {
    int ecl = hi - 1;
    int ek = lo + kk;
    int iv = src[ek < ecl ? ek : ecl];

    for (int e0 = lo; e0 < hi; e0 += 8) {
      // prefetch next batch's src indices
      int e0n = e0 + 8;
      int ekn = e0n + kk;
      int ivn = (e0n < hi) ? src[ekn < ecl ? ekn : ecl] : iv;

      // broadcast the 8 src indices (SGPR bases for the x-gathers)
      int j0 = __builtin_amdgcn_readlane(iv, 0);
      int j1 = __builtin_amdgcn_readlane(iv, 8);
      int j2 = __builtin_amdgcn_readlane(iv, 16);
      int j3 = __builtin_amdgcn_readlane(iv, 24);
      int j4 = __builtin_amdgcn_readlane(iv, 32);
      int j5 = __builtin_amdgcn_readlane(iv, 40);
      int j6 = __builtin_amdgcn_readlane(iv, 48);
      int j7 = __builtin_amdgcn_readlane(iv, 56);

      // e^{t}[src][mm] gather: 8 edges x 32B
      float tv = ST[iv * 16 + 8 + mm];

      // x-gathers (bf16 rows, 128B/wave each), 8 in flight
      float xv[8];
      xv[0] = __bfloat162float(xbf[(size_t)j0 * CDIM + lane]);
      xv[1] = __bfloat162float(xbf[(size_t)j1 * CDIM + lane]);
      xv[2] = __bfloat162float(xbf[(size_t)j2 * CDIM + lane]);
      xv[3] = __bfloat162float(xbf[(size_t)j3 * CDIM + lane]);
      xv[4] = __bfloat162float(xbf[(size_t)j4 * CDIM + lane]);
      xv[5] = __bfloat162float(xbf[(size_t)j5 * CDIM + lane]);
      xv[6] = __bfloat162float(xbf[(size_t)j6 * CDIM + lane]);
      xv[7] = __bfloat162float(xbf[(size_t)j7 * CDIM + lane]);

      // softmax numerator u*e^t; sum over mm within 8-lane group
      float w = uv * tv;
      float ssum = w + __shfl_xor(w, 1);
      ssum += __shfl_xor(ssum, 2);
      ssum += __shfl_xor(ssum, 4);
      float qv = w * __frcp_rn(ssum);
      if (e0 + kk >= hi) qv = 0.f;  // padded slots contribute nothing
      racc += qv;

      // q broadcast via readlane (VALU), no LDS round-trip
#pragma unroll
      for (int k = 0; k < 8; ++k) {
        float xk = xv[k];
        g[0] = fmaf(rdlane(qv, k * 8 + 0), xk, g[0]);
        g[1] = fmaf(rdlane(qv, k * 8 + 1), xk, g[1]);
        g[2] = fmaf(rdlane(qv, k * 8 + 2), xk, g[2]);
        g[3] = fmaf(rdlane(qv, k * 8 + 3), xk, g[3]);
        g[4] = fmaf(rdlane(qv, k * 8 + 4), xk, g[4]);
        g[5] = fmaf(rdlane(qv, k * 8 + 5), xk, g[5]);
        g[6] = fmaf(rdlane(qv, k * 8 + 6), xk, g[6]);
        g[7] = fmaf(rdlane(qv, k * 8 + 7), xk, g[7]);
      }
      iv = ivn;
    }
  }

  __hip_bfloat16* Gi = Gbf + (size_t)i * 512;
#pragma unroll
  for (int m = 0; m < 8; ++m) Gi[m * 64 + lane] = __float2bfloat16(g[m]);

  racc += __shfl_xor(racc, 8);
  racc += __shfl_xor(racc, 16);
  racc += __shfl_xor(racc, 32);
  if (lane < 8) R[(size_t)i * 8 + lane] = racc;
}

// out[N,64] = (Gbf[N,512] @ Wcat[512,64] + R[N,8] @ b[8,64]) / 8 via bf16 MFMA.
// B-frags read directly from WtB in global (64 KB, L2-hot): no LDS, no barrier.
// Layouts (gfx950 16x16x32 bf16, m89/m120-verified):
//   A: a[j]=A[lane&15][q*8+j], q=lane>>4 ; B: b[j]=B[q*8+j][lane&15]
//   D: reg v -> row=q*4+v, col=lane&15
__global__ __launch_bounds__(256) void k4_mfma(
    const __hip_bfloat16* __restrict__ Gbf, const float* __restrict__ R,
    const __hip_bfloat16* __restrict__ WtB, const float* __restrict__ bias,
    float* __restrict__ out, int N) {
  int wave = threadIdx.x >> 6;
  int lane = threadIdx.x & 63;
  int r0 = (blockIdx.x * 4 + wave) * 16;
  if (r0 >= N) return;

  int m = lane & 15;
  int q = lane >> 4;
  const __bf16* abase = (const __bf16*)(Gbf + (size_t)(r0 + m) * 512) + q * 8;
  const __bf16* wbase = (const __bf16*)WtB + (size_t)m * 512 + q * 8;

  f32x4 acc0 = {0, 0, 0, 0}, acc1 = {0, 0, 0, 0};
  f32x4 acc2 = {0, 0, 0, 0}, acc3 = {0, 0, 0, 0};
#pragma unroll
  for (int kt = 0; kt < 16; ++kt) {
    bf16x8 a = *(const bf16x8*)(abase + kt * 32);
    bf16x8 b0 = *(const bf16x8*)(wbase + 0 * 16 * 512 + kt * 32);
    bf16x8 b1 = *(const bf16x8*)(wbase + 1 * 16 * 512 + kt * 32);
    bf16x8 b2 = *(const bf16x8*)(wbase + 2 * 16 * 512 + kt * 32);
    bf16x8 b3 = *(const bf16x8*)(wbase + 3 * 16 * 512 + kt * 32);
    acc0 = __builtin_amdgcn_mfma_f32_16x16x32_bf16(a, b0, acc0, 0, 0, 0);
    acc1 = __builtin_amdgcn_mfma_f32_16x16x32_bf16(a, b1, acc1, 0, 0, 0);
    acc2 = __builtin_amdgcn_mfma_f32_16x16x32_bf16(a, b2, acc2, 0, 0, 0);
    acc3 = __builtin_amdgcn_mfma_f32_16x16x32_bf16(a, b3, acc3, 0, 0, 0);
  }

#pragma unroll
  for (int v = 0; v < 4; ++v) {
    int ri = r0 + q * 4 + v;
    if (ri >= N) continue;
    const float* Ri = R + (size_t)ri * 8;
    float b0s = 0, b1s = 0, b2s = 0, b3s = 0;
#pragma unroll
    for (int mm = 0; mm < 8; ++mm) {
      float rv = Ri[mm];
      b0s = fmaf(rv, bias[mm * 64 + 0 + m], b0s);
      b1s = fmaf(rv, bias[mm * 64 + 16 + m], b1s);
      b2s = fmaf(rv, bias[mm * 64 + 32 + m], b2s);
      b3s = fmaf(rv, bias[mm * 64 + 48 + m], b3s);
    }
    float* orow = out + (size_t)ri * 64;
    orow[0 + m]  = (acc0[v] + b0s) * 0.125f;
    orow[16 + m] = (acc1[v] + b1s) * 0.125f;
    orow[32 + m] = (acc2[v] + b2s) * 0.125f;
    orow[48 + m] = (acc3[v] + b3s) * 0.125f;
  }
}

extern "C" void kernel_launch(void* const* d_in, const int* in_sizes, int n_in,
                              void* d_out, int out_size, void* d_ws, size_t ws_size,
                              hipStream_t stream) {
  const float* x  = (const float*)d_in[0];   // [N,64]
  const int* src  = (const int*)d_in[1];     // [E]
  const int* dst  = (const int*)d_in[2];     // [E] sorted
  const float* W  = (const float*)d_in[3];   // [8,64,64] == Wcat[512,64]
  const float* b  = (const float*)d_in[4];   // [8,64]
  const float* Ws = (const float*)d_in[5];   // [64,8]
  const float* bs = (const float*)d_in[6];   // [8]
  const float* Wt = (const float*)d_in[7];   // [64,8]
  const float* bt = (const float*)d_in[8];   // [8]
  int N = in_sizes[0] / CDIM;
  int E = in_sizes[1];
  float* out = (float*)d_out;

  float* ST = (float*)d_ws;                                      // N*16 f32
  __hip_bfloat16* Gbf = (__hip_bfloat16*)(ST + (size_t)N * 16);  // N*512 bf16
  float* R  = (float*)(Gbf + (size_t)N * 512);                   // N*8 f32
  __hip_bfloat16* WtB = (__hip_bfloat16*)(R + (size_t)N * 8);    // 64*512 bf16
  __hip_bfloat16* xbf = WtB + 64 * 512;                          // N*64 bf16
  int* rowptr = (int*)(xbf + (size_t)N * CDIM);                  // N+1 i32

  int nb1 = (N * 16 + 255) / 256;
  int nbE = (E + 255) / 256;
  k1_pre<<<nb1 + 128 + nbE, 256, 0, stream>>>(x, Ws, bs, Wt, bt, W, dst, ST,
                                              xbf, WtB, rowptr, N, E, nb1);
  k3_fused<<<(N + 3) / 4, 256, 0, stream>>>(xbf, src, rowptr, ST, Gbf, R, N);
  int mtiles = (N + 15) / 16;
  k4_mfma<<<(mtiles + 3) / 4, 256, 0, stream>>>(Gbf, R, WtB, b, out, N);
}

// Round 8
// 209.497 us; speedup vs baseline: 1.0182x; 1.0182x over previous
//
#include <hip/hip_runtime.h>
#include <hip/hip_bf16.h>

// FeaStNet NeighbourAssignment — 2 launches:
//   k1_pre : ST[i][0:8]=s_i, ST[i][8:16]=exp(t_i) ; xbf=bf16(x) ;
//            WtB=bf16(Wcat^T) ; rowptr from sorted dst
//   k3_full: block = 16 nodes (4 per wave).
//     Phase 1 (per wave, per node): 8-edge batches, inline softmax
//       q[e][m] = e^{s_m} * et[src[e]][m] / sum_m   (q via wave-private LDS
//       broadcast), g[m][c] += q * xbf[src[e]][c] in registers; g -> LDS
//       tile gt[16][520] (bf16), R -> LDS rl[16][8].
//     Phase 2 (after one barrier): wave w computes out rows 0..15, cols
//       16w..16w+15 via one 16x16x32 bf16 MFMA chain (A from LDS, B from
//       L2-hot WtB), epilogue adds R@b and scales by 1/8.
//   No Gbf/R HBM round-trip, no separate GEMM kernel.

#define CDIM 64
#define SDIM 8

typedef __bf16 bf16x8 __attribute__((ext_vector_type(8)));
typedef float f32x4 __attribute__((ext_vector_type(4)));

// blocks [0,nb1): ST + xbf ; [nb1,nb1+128): WtB ; [nb1+128, +nbE): rowptr
__global__ __launch_bounds__(256) void k1_pre(
    const float* __restrict__ x, const float* __restrict__ Ws,
    const float* __restrict__ bs, const float* __restrict__ Wt,
    const float* __restrict__ bt, const float* __restrict__ W,
    const int* __restrict__ dst, float* __restrict__ ST,
    __hip_bfloat16* __restrict__ xbf, __hip_bfloat16* __restrict__ WtB,
    int* __restrict__ rowptr, int N, int E, int nb1) {
  int bid = blockIdx.x;
  if (bid >= nb1 + 128) {  // rowptr build (dst sorted)
    int e = (bid - nb1 - 128) * 256 + threadIdx.x;
    if (e >= E) return;
    int a = dst[e];
    int bnd = (e + 1 < E) ? dst[e + 1] : N;
    if (e == 0) {
      for (int d = 0; d <= a; ++d) rowptr[d] = 0;
    }
    for (int d = a + 1; d <= bnd; ++d) rowptr[d] = e + 1;
    return;
  }
  if (bid >= nb1) {  // Wcat[512][64] -> WtB[64][512] bf16
    int t = (bid - nb1) * 256 + threadIdx.x;  // 0..32767
    int o = t >> 9, k = t & 511;
    WtB[t] = __float2bfloat16(W[(size_t)k * 64 + o]);
    return;
  }
  int tid = bid * 256 + threadIdx.x;
  int i = tid >> 4, m = tid & 15;
  if (i >= N) return;
  int mm = m & 7;
  const float* Wp = (m < 8) ? Ws : Wt;
  float acc = (m < 8) ? bs[mm] : bt[mm];
  const float* xr = x + (size_t)i * CDIM;
#pragma unroll
  for (int c = 0; c < CDIM; ++c) acc += xr[c] * Wp[c * SDIM + mm];
  // t-half stored as exp(t); s+t is O(1) so e^z is fp32-safe
  ST[i * 16 + m] = (m < 8) ? acc : __expf(acc);
  float4 xv4 = *(const float4*)(xr + m * 4);
  union { __hip_bfloat16 h[4]; ushort4 u; } cv;
  cv.h[0] = __float2bfloat16(xv4.x);
  cv.h[1] = __float2bfloat16(xv4.y);
  cv.h[2] = __float2bfloat16(xv4.z);
  cv.h[3] = __float2bfloat16(xv4.w);
  *(ushort4*)(xbf + (size_t)i * CDIM + m * 4) = cv.u;
}

// Layouts (gfx950 16x16x32 bf16, m89/m120-verified):
//   A: a[j]=A[lane&15][q*8+j], q=lane>>4 ; B: b[j]=B[q*8+j][lane&15]
//   D: reg v -> row=q*4+v, col=lane&15
__global__ __launch_bounds__(256) void k3_full(
    const __hip_bfloat16* __restrict__ xbf, const int* __restrict__ src,
    const int* __restrict__ rowptr, const float* __restrict__ ST,
    const __hip_bfloat16* __restrict__ WtB, const float* __restrict__ bias,
    float* __restrict__ out, int N) {
  __shared__ __hip_bfloat16 gt[16][520];  // [node][k], pad 8 (row = 65x16B)
  __shared__ float rl[16][8];             // [node][m]
  __shared__ float qlds[4][64];           // wave-private q broadcast

  int wave = threadIdx.x >> 6;
  int lane = threadIdx.x & 63;
  int mm = lane & 7;
  int kk = lane >> 3;
  int base = blockIdx.x * 16;
  float* qw = &qlds[wave][0];

  // ---- Phase 1: gather 4 nodes per wave ----
  for (int t = 0; t < 4; ++t) {
    int i = base + wave * 4 + t;
    float g[8] = {0, 0, 0, 0, 0, 0, 0, 0};
    float racc = 0.f;
    if (i < N) {
      int lo = rowptr[i];
      int hi = rowptr[i + 1];
      float uv = __expf(ST[i * 16 + mm]);  // e^{s_m}, wave-resident

      if (lo < hi) {
        int ecl = hi - 1;
        int ek = lo + kk;
        int iv = src[ek < ecl ? ek : ecl];

        for (int e0 = lo; e0 < hi; e0 += 8) {
          // prefetch next batch's src indices
          int e0n = e0 + 8;
          int ekn = e0n + kk;
          int ivn = (e0n < hi) ? src[ekn < ecl ? ekn : ecl] : iv;

          // broadcast the 8 src indices (SGPR bases for the x-gathers)
          int j0 = __builtin_amdgcn_readlane(iv, 0);
          int j1 = __builtin_amdgcn_readlane(iv, 8);
          int j2 = __builtin_amdgcn_readlane(iv, 16);
          int j3 = __builtin_amdgcn_readlane(iv, 24);
          int j4 = __builtin_amdgcn_readlane(iv, 32);
          int j5 = __builtin_amdgcn_readlane(iv, 40);
          int j6 = __builtin_amdgcn_readlane(iv, 48);
          int j7 = __builtin_amdgcn_readlane(iv, 56);

          // e^{t}[src][mm] gather: 8 edges x 32B
          float tv = ST[iv * 16 + 8 + mm];

          // x-gathers (bf16 rows, 128B/wave each), 8 in flight
          float xv[8];
          xv[0] = __bfloat162float(xbf[(size_t)j0 * CDIM + lane]);
          xv[1] = __bfloat162float(xbf[(size_t)j1 * CDIM + lane]);
          xv[2] = __bfloat162float(xbf[(size_t)j2 * CDIM + lane]);
          xv[3] = __bfloat162float(xbf[(size_t)j3 * CDIM + lane]);
          xv[4] = __bfloat162float(xbf[(size_t)j4 * CDIM + lane]);
          xv[5] = __bfloat162float(xbf[(size_t)j5 * CDIM + lane]);
          xv[6] = __bfloat162float(xbf[(size_t)j6 * CDIM + lane]);
          xv[7] = __bfloat162float(xbf[(size_t)j7 * CDIM + lane]);

          // softmax: numerator e^s * e^t, sum within 8-lane group
          float w = uv * tv;
          float ssum = w + __shfl_xor(w, 1);
          ssum += __shfl_xor(ssum, 2);
          ssum += __shfl_xor(ssum, 4);
          float qv = w * __frcp_rn(ssum);
          if (e0 + kk >= hi) qv = 0.f;  // padded slots contribute nothing
          racc += qv;
          qw[lane] = qv;  // stage for broadcast reads (LDS pipe, off VALU)

#pragma unroll
          for (int k = 0; k < 8; ++k) {
            float4 qa = *(const float4*)(qw + k * 8);
            float4 qb = *(const float4*)(qw + k * 8 + 4);
            float xk = xv[k];
            g[0] = fmaf(qa.x, xk, g[0]);
            g[1] = fmaf(qa.y, xk, g[1]);
            g[2] = fmaf(qa.z, xk, g[2]);
            g[3] = fmaf(qa.w, xk, g[3]);
            g[4] = fmaf(qb.x, xk, g[4]);
            g[5] = fmaf(qb.y, xk, g[5]);
            g[6] = fmaf(qb.z, xk, g[6]);
            g[7] = fmaf(qb.w, xk, g[7]);
          }
          iv = ivn;
        }
      }
    }
    // stash g (bf16) + R into the block tile
    int nl = wave * 4 + t;
#pragma unroll
    for (int m = 0; m < 8; ++m) gt[nl][m * 64 + lane] = __float2bfloat16(g[m]);
    racc += __shfl_xor(racc, 8);
    racc += __shfl_xor(racc, 16);
    racc += __shfl_xor(racc, 32);
    if (lane < 8) rl[nl][lane] = racc;
  }

  __syncthreads();

  // ---- Phase 2: out[base..base+16, 16w..16w+16) via one MFMA chain ----
  int row = lane & 15;  // A row (node_local) == B col within this wave's slice
  int q = lane >> 4;
  int c0 = wave * 16;
  const __bf16* ab = (const __bf16*)&gt[row][0] + q * 8;
  const __bf16* wb = (const __bf16*)WtB + (size_t)(c0 + row) * 512 + q * 8;

  f32x4 acc = {0, 0, 0, 0};
#pragma unroll
  for (int kt = 0; kt < 16; ++kt) {
    bf16x8 a = *(const bf16x8*)(ab + kt * 32);
    bf16x8 b = *(const bf16x8*)(wb + kt * 32);
    acc = __builtin_amdgcn_mfma_f32_16x16x32_bf16(a, b, acc, 0, 0, 0);
  }

#pragma unroll
  for (int v = 0; v < 4; ++v) {
    int nl = q * 4 + v;
    int i = base + nl;
    if (i >= N) continue;
    float bsum = 0.f;
#pragma unroll
    for (int m = 0; m < 8; ++m)
      bsum = fmaf(rl[nl][m], bias[m * 64 + c0 + row], bsum);
    out[(size_t)i * 64 + c0 + row] = (acc[v] + bsum) * 0.125f;
  }
}

extern "C" void kernel_launch(void* const* d_in, const int* in_sizes, int n_in,
                              void* d_out, int out_size, void* d_ws, size_t ws_size,
                              hipStream_t stream) {
  const float* x  = (const float*)d_in[0];   // [N,64]
  const int* src  = (const int*)d_in[1];     // [E]
  const int* dst  = (const int*)d_in[2];     // [E] sorted
  const float* W  = (const float*)d_in[3];   // [8,64,64] == Wcat[512,64]
  const float* b  = (const float*)d_in[4];   // [8,64]
  const float* Ws = (const float*)d_in[5];   // [64,8]
  const float* bs = (const float*)d_in[6];   // [8]
  const float* Wt = (const float*)d_in[7];   // [64,8]
  const float* bt = (const float*)d_in[8];   // [8]
  int N = in_sizes[0] / CDIM;
  int E = in_sizes[1];
  float* out = (float*)d_out;

  float* ST = (float*)d_ws;                                      // N*16 f32
  __hip_bfloat16* WtB = (__hip_bfloat16*)(ST + (size_t)N * 16);  // 64*512 bf16
  __hip_bfloat16* xbf = WtB + 64 * 512;                          // N*64 bf16
  int* rowptr = (int*)(xbf + (size_t)N * CDIM);                  // N+1 i32

  int nb1 = (N * 16 + 255) / 256;
  int nbE = (E + 255) / 256;
  k1_pre<<<nb1 + 128 + nbE, 256, 0, stream>>>(x, Ws, bs, Wt, bt, W, dst, ST,
                                              xbf, WtB, rowptr, N, E, nb1);
  k3_full<<<(N + 15) / 16, 256, 0, stream>>>(xbf, src, rowptr, ST, WtB, b,
                                             out, N);
}

// Round 9
// 160.077 us; speedup vs baseline: 1.3326x; 1.3087x over previous
//
#include <hip/hip_runtime.h>
#include <hip/hip_bf16.h>

// FeaStNet NeighbourAssignment — 3 launches:
//   k1_pre : ST[i][0:8]=s_i, ST[i][8:16]=exp(t_i) via bf16 MFMA
//            ([64,64]@[64,16] per block); xbf=bf16(x) produced from the same
//            loads; WtB=bf16(Wcat^T); rowptr from sorted dst.
//   k3_fused: one wave per node, 8-edge batches, inline softmax
//            q[e][m] = e^{s_m} * et[src[e]][m] / sum   (q broadcast via
//            wave-private LDS — LDS pipe, off the VALU critical path),
//            g[m][c] accumulated in registers -> Gbf, R.
//   k4_mfma: out = (Gbf @ Wcat + R @ b)/8 via bf16 MFMA, W^T tile in LDS.

#define CDIM 64
#define SDIM 8

typedef __bf16 bf16x8 __attribute__((ext_vector_type(8)));
typedef float f32x4 __attribute__((ext_vector_type(4)));

// blocks [0,nbN): ST+xbf via MFMA ; [nbN,nbN+128): WtB ; rest: rowptr
__global__ __launch_bounds__(256) void k1_pre(
    const float* __restrict__ x, const float* __restrict__ Ws,
    const float* __restrict__ bs, const float* __restrict__ Wt,
    const float* __restrict__ bt, const float* __restrict__ W,
    const int* __restrict__ dst, float* __restrict__ ST,
    __hip_bfloat16* __restrict__ xbf, __hip_bfloat16* __restrict__ WtB,
    int* __restrict__ rowptr, int N, int E, int nbN) {
  int bid = blockIdx.x;
  if (bid >= nbN + 128) {  // rowptr build (dst sorted)
    int e = (bid - nbN - 128) * 256 + threadIdx.x;
    if (e >= E) return;
    int a = dst[e];
    int bnd = (e + 1 < E) ? dst[e + 1] : N;
    if (e == 0) {
      for (int d = 0; d <= a; ++d) rowptr[d] = 0;
    }
    for (int d = a + 1; d <= bnd; ++d) rowptr[d] = e + 1;
    return;
  }
  if (bid >= nbN) {  // Wcat[512][64] -> WtB[64][512] bf16
    int t = (bid - nbN) * 256 + threadIdx.x;  // 0..32767
    int o = t >> 9, k = t & 511;
    WtB[t] = __float2bfloat16(W[(size_t)k * 64 + o]);
    return;
  }

  // ---- ST + xbf for 64 nodes via MFMA ----
  __shared__ __hip_bfloat16 wst[16 * 72];  // WstT[n][k], stride 72 (16B-aligned rows)
  __shared__ float bst[16];
  int t = threadIdx.x;
#pragma unroll
  for (int j = 0; j < 4; ++j) {
    int idx = t * 4 + j;  // 0..1023
    int n = idx >> 6, k = idx & 63;
    float v = (n < 8) ? Ws[k * 8 + n] : Wt[k * 8 + (n - 8)];
    wst[n * 72 + k] = __float2bfloat16(v);
  }
  if (t < 16) bst[t] = (t < 8) ? bs[t] : bt[t - 8];
  __syncthreads();

  int wave = t >> 6, lane = t & 63;
  int r = lane & 15, q = lane >> 4;
  int node = bid * 64 + wave * 16 + r;
  int nodec = node < N ? node : N - 1;
  const float* xr = x + (size_t)nodec * CDIM;

  bf16x8 afrag[2];
#pragma unroll
  for (int kt = 0; kt < 2; ++kt) {
    float4 u0 = *(const float4*)(xr + kt * 32 + q * 8);
    float4 u1 = *(const float4*)(xr + kt * 32 + q * 8 + 4);
    union { bf16x8 v; __hip_bfloat16 h[8]; } a;
    a.h[0] = __float2bfloat16(u0.x); a.h[1] = __float2bfloat16(u0.y);
    a.h[2] = __float2bfloat16(u0.z); a.h[3] = __float2bfloat16(u0.w);
    a.h[4] = __float2bfloat16(u1.x); a.h[5] = __float2bfloat16(u1.y);
    a.h[6] = __float2bfloat16(u1.z); a.h[7] = __float2bfloat16(u1.w);
    afrag[kt] = a.v;
    if (node < N)
      *(bf16x8*)(xbf + (size_t)node * CDIM + kt * 32 + q * 8) = a.v;
  }

  // B-frags from LDS: b[j] = WstT[n=lane&15][kt*32 + q*8 + j]
  bf16x8 bf0 = *(const bf16x8*)(wst + r * 72 + q * 8);
  bf16x8 bf1 = *(const bf16x8*)(wst + r * 72 + 32 + q * 8);

  f32x4 acc = {0, 0, 0, 0};
  acc = __builtin_amdgcn_mfma_f32_16x16x32_bf16(afrag[0], bf0, acc, 0, 0, 0);
  acc = __builtin_amdgcn_mfma_f32_16x16x32_bf16(afrag[1], bf1, acc, 0, 0, 0);

  // D: reg v -> row(node-local)=q*4+v, col(st index)=lane&15
  int m = lane & 15;
#pragma unroll
  for (int v = 0; v < 4; ++v) {
    int nd = bid * 64 + wave * 16 + q * 4 + v;
    if (nd >= N) continue;
    float val = acc[v] + bst[m];
    if (m >= 8) val = __expf(val);  // store exp(t); s+t is O(1), fp32-safe
    ST[nd * 16 + m] = val;
  }
}

// One wave per node. 8-edge batches; lane -> (kk=lane>>3, mm=lane&7).
__global__ __launch_bounds__(256) void k3_fused(
    const __hip_bfloat16* __restrict__ xbf, const int* __restrict__ src,
    const int* __restrict__ rowptr, const float* __restrict__ ST,
    __hip_bfloat16* __restrict__ Gbf, float* __restrict__ R, int N) {
  __shared__ float qlds[4][64];
  int wave = __builtin_amdgcn_readfirstlane(threadIdx.x >> 6);
  int lane = threadIdx.x & 63;
  int i = blockIdx.x * 4 + wave;
  if (i >= N) return;  // wave-private LDS, no barriers

  int lo = rowptr[i];
  int hi = rowptr[i + 1];
  int mm = lane & 7;
  int kk = lane >> 3;

  float uv = __expf(ST[i * 16 + mm]);  // e^{s_m}, wave-resident

  float g[8] = {0, 0, 0, 0, 0, 0, 0, 0};
  float racc = 0.f;
  float* qw = &qlds[wave][0];

  if (lo < hi) {
    int ecl = hi - 1;
    int ek = lo + kk;
    int iv = src[ek < ecl ? ek : ecl];

    for (int e0 = lo; e0 < hi; e0 += 8) {
      // prefetch next batch's src indices
      int e0n = e0 + 8;
      int ekn = e0n + kk;
      int ivn = (e0n < hi) ? src[ekn < ecl ? ekn : ecl] : iv;

      // broadcast the 8 src indices (SGPR bases for the x-gathers)
      int j0 = __builtin_amdgcn_readlane(iv, 0);
      int j1 = __builtin_amdgcn_readlane(iv, 8);
      int j2 = __builtin_amdgcn_readlane(iv, 16);
      int j3 = __builtin_amdgcn_readlane(iv, 24);
      int j4 = __builtin_amdgcn_readlane(iv, 32);
      int j5 = __builtin_amdgcn_readlane(iv, 40);
      int j6 = __builtin_amdgcn_readlane(iv, 48);
      int j7 = __builtin_amdgcn_readlane(iv, 56);

      // e^{t}[src][mm] gather: 8 edges x 32B
      float tv = ST[iv * 16 + 8 + mm];

      // x-gathers (bf16 rows, 128B/wave each), 8 in flight
      float xv[8];
      xv[0] = __bfloat162float(xbf[(size_t)j0 * CDIM + lane]);
      xv[1] = __bfloat162float(xbf[(size_t)j1 * CDIM + lane]);
      xv[2] = __bfloat162float(xbf[(size_t)j2 * CDIM + lane]);
      xv[3] = __bfloat162float(xbf[(size_t)j3 * CDIM + lane]);
      xv[4] = __bfloat162float(xbf[(size_t)j4 * CDIM + lane]);
      xv[5] = __bfloat162float(xbf[(size_t)j5 * CDIM + lane]);
      xv[6] = __bfloat162float(xbf[(size_t)j6 * CDIM + lane]);
      xv[7] = __bfloat162float(xbf[(size_t)j7 * CDIM + lane]);

      // softmax: numerator e^s * e^t, sum within 8-lane group
      float w = uv * tv;
      float ssum = w + __shfl_xor(w, 1);
      ssum += __shfl_xor(ssum, 2);
      ssum += __shfl_xor(ssum, 4);
      float qv = w * __frcp_rn(ssum);
      if (e0 + kk >= hi) qv = 0.f;  // padded slots contribute nothing
      racc += qv;
      qw[lane] = qv;  // stage for broadcast reads (LDS pipe, off VALU)

#pragma unroll
      for (int k = 0; k < 8; ++k) {
        float4 qa = *(const float4*)(qw + k * 8);
        float4 qb = *(const float4*)(qw + k * 8 + 4);
        float xk = xv[k];
        g[0] = fmaf(qa.x, xk, g[0]);
        g[1] = fmaf(qa.y, xk, g[1]);
        g[2] = fmaf(qa.z, xk, g[2]);
        g[3] = fmaf(qa.w, xk, g[3]);
        g[4] = fmaf(qb.x, xk, g[4]);
        g[5] = fmaf(qb.y, xk, g[5]);
        g[6] = fmaf(qb.z, xk, g[6]);
        g[7] = fmaf(qb.w, xk, g[7]);
      }
      iv = ivn;
    }
  }

  __hip_bfloat16* Gi = Gbf + (size_t)i * 512;
#pragma unroll
  for (int m = 0; m < 8; ++m) Gi[m * 64 + lane] = __float2bfloat16(g[m]);

  racc += __shfl_xor(racc, 8);
  racc += __shfl_xor(racc, 16);
  racc += __shfl_xor(racc, 32);
  if (lane < 8) R[(size_t)i * 8 + lane] = racc;
}

// out[N,64] = (Gbf[N,512] @ Wcat[512,64] + R[N,8] @ b[8,64]) / 8 via bf16 MFMA.
// WtB = Wcat^T [64][512] bf16, staged in LDS row-stride 520 (pad 8).
// Layouts (gfx950 16x16x32 bf16, m89/m120-verified):
//   A: a[j]=A[lane&15][q*8+j], q=lane>>4 ; B: b[j]=B[q*8+j][lane&15]
//   D: reg v -> row=q*4+v, col=lane&15
__global__ __launch_bounds__(256) void k4_mfma(
    const __hip_bfloat16* __restrict__ Gbf, const float* __restrict__ R,
    const __hip_bfloat16* __restrict__ WtB, const float* __restrict__ bias,
    float* __restrict__ out, int N) {
  __shared__ float4 btile[64 * 65];  // [n][k] bf16, row = 520 bf16 = 65 float4
  {
    const float4* srcp = (const float4*)WtB;  // 4096 float4
    int t = threadIdx.x;
#pragma unroll
    for (int j = 0; j < 16; ++j) {
      int ci = t + j * 256;
      btile[(ci >> 6) * 65 + (ci & 63)] = srcp[ci];
    }
  }
  __syncthreads();

  int wave = threadIdx.x >> 6;
  int lane = threadIdx.x & 63;
  int r0 = (blockIdx.x * 4 + wave) * 16;
  if (r0 >= N) return;

  int m = lane & 15;
  int q = lane >> 4;
  const __bf16* abase = (const __bf16*)(Gbf + (size_t)(r0 + m) * 512) + q * 8;
  const __bf16* lbase = (const __bf16*)btile + (size_t)m * 520 + q * 8;

  f32x4 acc0 = {0, 0, 0, 0}, acc1 = {0, 0, 0, 0};
  f32x4 acc2 = {0, 0, 0, 0}, acc3 = {0, 0, 0, 0};
#pragma unroll
  for (int kt = 0; kt < 16; ++kt) {
    bf16x8 a = *(const bf16x8*)(abase + kt * 32);
    bf16x8 b0 = *(const bf16x8*)(lbase + 0 * 520 + kt * 32);
    bf16x8 b1 = *(const bf16x8*)(lbase + 16 * 520 + kt * 32);
    bf16x8 b2 = *(const bf16x8*)(lbase + 32 * 520 + kt * 32);
    bf16x8 b3 = *(const bf16x8*)(lbase + 48 * 520 + kt * 32);
    acc0 = __builtin_amdgcn_mfma_f32_16x16x32_bf16(a, b0, acc0, 0, 0, 0);
    acc1 = __builtin_amdgcn_mfma_f32_16x16x32_bf16(a, b1, acc1, 0, 0, 0);
    acc2 = __builtin_amdgcn_mfma_f32_16x16x32_bf16(a, b2, acc2, 0, 0, 0);
    acc3 = __builtin_amdgcn_mfma_f32_16x16x32_bf16(a, b3, acc3, 0, 0, 0);
  }

#pragma unroll
  for (int v = 0; v < 4; ++v) {
    int ri = r0 + q * 4 + v;
    if (ri >= N) continue;
    const float* Ri = R + (size_t)ri * 8;
    float b0s = 0, b1s = 0, b2s = 0, b3s = 0;
#pragma unroll
    for (int mm = 0; mm < 8; ++mm) {
      float rv = Ri[mm];
      b0s = fmaf(rv, bias[mm * 64 + 0 + m], b0s);
      b1s = fmaf(rv, bias[mm * 64 + 16 + m], b1s);
      b2s = fmaf(rv, bias[mm * 64 + 32 + m], b2s);
      b3s = fmaf(rv, bias[mm * 64 + 48 + m], b3s);
    }
    float* orow = out + (size_t)ri * 64;
    orow[0 + m]  = (acc0[v] + b0s) * 0.125f;
    orow[16 + m] = (acc1[v] + b1s) * 0.125f;
    orow[32 + m] = (acc2[v] + b2s) * 0.125f;
    orow[48 + m] = (acc3[v] + b3s) * 0.125f;
  }
}

extern "C" void kernel_launch(void* const* d_in, const int* in_sizes, int n_in,
                              void* d_out, int out_size, void* d_ws, size_t ws_size,
                              hipStream_t stream) {
  const float* x  = (const float*)d_in[0];   // [N,64]
  const int* src  = (const int*)d_in[1];     // [E]
  const int* dst  = (const int*)d_in[2];     // [E] sorted
  const float* W  = (const float*)d_in[3];   // [8,64,64] == Wcat[512,64]
  const float* b  = (const float*)d_in[4];   // [8,64]
  const float* Ws = (const float*)d_in[5];   // [64,8]
  const float* bs = (const float*)d_in[6];   // [8]
  const float* Wt = (const float*)d_in[7];   // [64,8]
  const float* bt = (const float*)d_in[8];   // [8]
  int N = in_sizes[0] / CDIM;
  int E = in_sizes[1];
  float* out = (float*)d_out;

  float* ST = (float*)d_ws;                                      // N*16 f32
  __hip_bfloat16* Gbf = (__hip_bfloat16*)(ST + (size_t)N * 16);  // N*512 bf16
  float* R  = (float*)(Gbf + (size_t)N * 512);                   // N*8 f32
  __hip_bfloat16* WtB = (__hip_bfloat16*)(R + (size_t)N * 8);    // 64*512 bf16
  __hip_bfloat16* xbf = WtB + 64 * 512;                          // N*64 bf16
  int* rowptr = (int*)(xbf + (size_t)N * CDIM);                  // N+1 i32

  int nbN = (N + 63) / 64;
  int nbE = (E + 255) / 256;
  k1_pre<<<nbN + 128 + nbE, 256, 0, stream>>>(x, Ws, bs, Wt, bt, W, dst, ST,
                                              xbf, WtB, rowptr, N, E, nbN);
  k3_fused<<<(N + 3) / 4, 256, 0, stream>>>(xbf, src, rowptr, ST, Gbf, R, N);
  int mtiles = (N + 15) / 16;
  k4_mfma<<<(mtiles + 3) / 4, 256, 0, stream>>>(Gbf, R, WtB, b, out, N);
}

// Round 10
// 156.758 us; speedup vs baseline: 1.3608x; 1.0212x over previous
//
#include <hip/hip_runtime.h>
#include <hip/hip_bf16.h>

// FeaStNet NeighbourAssignment — 3 launches:
//   k1_pre : ST[i][0:8]=s_i, ST[i][8:16]=exp(t_i) via bf16 MFMA;
//            xbf=bf16(x); WtB=bf16(Wcat^T); rowptr from sorted dst.
//   k3_mfma: one wave per node. 32-edge chunks:
//            q[e][m]=e^{s_m}*et[src[e]][m]/sum (8-lane-group softmax),
//            q(bf16)->qt[16][40] LDS (transposed), x rows->xt[32][72] LDS,
//            G[16,64] += QT[16,32] @ X[32,64] via 4x mfma 16x16x32 per chunk.
//            Padded slots: q=0, src clamped to a real edge (0*finite=0).
//   k4_mfma: out = (Gbf @ Wcat + R @ b)/8 via bf16 MFMA, W^T tile in LDS.

#define CDIM 64
#define SDIM 8

typedef __bf16 bf16x8 __attribute__((ext_vector_type(8)));
typedef float f32x4 __attribute__((ext_vector_type(4)));

// blocks [0,nbN): ST+xbf via MFMA ; [nbN,nbN+128): WtB ; rest: rowptr
__global__ __launch_bounds__(256) void k1_pre(
    const float* __restrict__ x, const float* __restrict__ Ws,
    const float* __restrict__ bs, const float* __restrict__ Wt,
    const float* __restrict__ bt, const float* __restrict__ W,
    const int* __restrict__ dst, float* __restrict__ ST,
    __hip_bfloat16* __restrict__ xbf, __hip_bfloat16* __restrict__ WtB,
    int* __restrict__ rowptr, int N, int E, int nbN) {
  int bid = blockIdx.x;
  if (bid >= nbN + 128) {  // rowptr build (dst sorted)
    int e = (bid - nbN - 128) * 256 + threadIdx.x;
    if (e >= E) return;
    int a = dst[e];
    int bnd = (e + 1 < E) ? dst[e + 1] : N;
    if (e == 0) {
      for (int d = 0; d <= a; ++d) rowptr[d] = 0;
    }
    for (int d = a + 1; d <= bnd; ++d) rowptr[d] = e + 1;
    return;
  }
  if (bid >= nbN) {  // Wcat[512][64] -> WtB[64][512] bf16
    int t = (bid - nbN) * 256 + threadIdx.x;  // 0..32767
    int o = t >> 9, k = t & 511;
    WtB[t] = __float2bfloat16(W[(size_t)k * 64 + o]);
    return;
  }

  // ---- ST + xbf for 64 nodes via MFMA ----
  __shared__ __hip_bfloat16 wst[16 * 72];  // WstT[n][k], stride 72
  __shared__ float bst[16];
  int t = threadIdx.x;
#pragma unroll
  for (int j = 0; j < 4; ++j) {
    int idx = t * 4 + j;  // 0..1023
    int n = idx >> 6, k = idx & 63;
    float v = (n < 8) ? Ws[k * 8 + n] : Wt[k * 8 + (n - 8)];
    wst[n * 72 + k] = __float2bfloat16(v);
  }
  if (t < 16) bst[t] = (t < 8) ? bs[t] : bt[t - 8];
  __syncthreads();

  int wave = t >> 6, lane = t & 63;
  int r = lane & 15, q = lane >> 4;
  int node = bid * 64 + wave * 16 + r;
  int nodec = node < N ? node : N - 1;
  const float* xr = x + (size_t)nodec * CDIM;

  bf16x8 afrag[2];
#pragma unroll
  for (int kt = 0; kt < 2; ++kt) {
    float4 u0 = *(const float4*)(xr + kt * 32 + q * 8);
    float4 u1 = *(const float4*)(xr + kt * 32 + q * 8 + 4);
    union { bf16x8 v; __hip_bfloat16 h[8]; } a;
    a.h[0] = __float2bfloat16(u0.x); a.h[1] = __float2bfloat16(u0.y);
    a.h[2] = __float2bfloat16(u0.z); a.h[3] = __float2bfloat16(u0.w);
    a.h[4] = __float2bfloat16(u1.x); a.h[5] = __float2bfloat16(u1.y);
    a.h[6] = __float2bfloat16(u1.z); a.h[7] = __float2bfloat16(u1.w);
    afrag[kt] = a.v;
    if (node < N)
      *(bf16x8*)(xbf + (size_t)node * CDIM + kt * 32 + q * 8) = a.v;
  }

  bf16x8 bf0 = *(const bf16x8*)(wst + r * 72 + q * 8);
  bf16x8 bf1 = *(const bf16x8*)(wst + r * 72 + 32 + q * 8);

  f32x4 acc = {0, 0, 0, 0};
  acc = __builtin_amdgcn_mfma_f32_16x16x32_bf16(afrag[0], bf0, acc, 0, 0, 0);
  acc = __builtin_amdgcn_mfma_f32_16x16x32_bf16(afrag[1], bf1, acc, 0, 0, 0);

  int m = lane & 15;
#pragma unroll
  for (int v = 0; v < 4; ++v) {
    int nd = bid * 64 + wave * 16 + q * 4 + v;
    if (nd >= N) continue;
    float val = acc[v] + bst[m];
    if (m >= 8) val = __expf(val);  // store exp(t)
    ST[nd * 16 + m] = val;
  }
}

// One wave per node; 32-edge chunks through MFMA.
// MFMA layouts (gfx950 16x16x32 bf16, m89/m120-verified):
//   A: a[j]=A[lane&15][(lane>>4)*8+j] ; B: b[j]=B[(lane>>4)*8+j][lane&15]
//   D: reg v -> row=(lane>>4)*4+v, col=lane&15
__global__ __launch_bounds__(256) void k3_mfma(
    const __hip_bfloat16* __restrict__ xbf, const int* __restrict__ src,
    const int* __restrict__ rowptr, const float* __restrict__ ST,
    __hip_bfloat16* __restrict__ Gbf, float* __restrict__ R, int N) {
  __shared__ __hip_bfloat16 qt_s[4][16 * 40];  // [wave][m'][k], stride 40
  __shared__ __hip_bfloat16 xt_s[4][32 * 72];  // [wave][e][c], stride 72

  int wave = threadIdx.x >> 6;
  int lane = threadIdx.x & 63;
  int i = blockIdx.x * 4 + wave;
  if (i >= N) return;  // wave-private LDS, no barriers

  int mm = lane & 7;   // m for softmax / channel-chunk for gather
  int kk = lane >> 3;  // edge-in-group for softmax & gather
  int mp = lane & 15;  // MFMA row/col
  int q3 = lane >> 4;  // MFMA quad

  __hip_bfloat16* qt = &qt_s[wave][0];
  __hip_bfloat16* xt = &xt_s[wave][0];

  // zero qt rows 8..15 once (A rows 8-15 -> D rows 8-15 = 0, never stored)
  __hip_bfloat16 z0 = __float2bfloat16(0.0f);
#pragma unroll
  for (int z = 0; z < 5; ++z) qt[320 + z * 64 + lane] = z0;

  int lo = rowptr[i];
  int hi = rowptr[i + 1];
  float uv = __expf(ST[i * 16 + mm]);  // e^{s_m}

  f32x4 acc0 = {0, 0, 0, 0}, acc1 = {0, 0, 0, 0};
  f32x4 acc2 = {0, 0, 0, 0}, acc3 = {0, 0, 0, 0};
  float racc = 0.f;

  if (lo < hi) {
    int ecl = hi - 1;
    int iv[4];
#pragma unroll
    for (int g = 0; g < 4; ++g) {
      int ek = lo + g * 8 + kk;
      iv[g] = src[ek < ecl ? ek : ecl];
    }

    for (int c0 = lo; c0 < hi; c0 += 32) {
      // x-gathers: lane loads 16B of its own edge's row (8 rows per instr)
      bf16x8 xv[4];
#pragma unroll
      for (int g = 0; g < 4; ++g)
        xv[g] = *(const bf16x8*)(xbf + (size_t)iv[g] * CDIM + mm * 8);

      // e^t gathers for softmax
      float tv[4];
#pragma unroll
      for (int g = 0; g < 4; ++g) tv[g] = ST[iv[g] * 16 + 8 + mm];

      // prefetch next chunk's src indices
      int nc0 = c0 + 32;
      int niv[4];
#pragma unroll
      for (int g = 0; g < 4; ++g) {
        int ek = nc0 + g * 8 + kk;
        ek = ek < ecl ? ek : ecl;
        niv[g] = (nc0 < hi) ? src[ek] : iv[g];
      }

      // softmax per 8-edge group; q -> qt (transposed, bf16)
#pragma unroll
      for (int g = 0; g < 4; ++g) {
        float w = uv * tv[g];
        float ssum = w + __shfl_xor(w, 1);
        ssum += __shfl_xor(ssum, 2);
        ssum += __shfl_xor(ssum, 4);
        float qv = w * __frcp_rn(ssum);
        if (c0 + g * 8 + kk >= hi) qv = 0.f;  // padded slot
        racc += qv;
        qt[mm * 40 + g * 8 + kk] = __float2bfloat16(qv);
      }

      // x rows -> xt[e][c]
#pragma unroll
      for (int g = 0; g < 4; ++g)
        *(bf16x8*)(xt + (g * 8 + kk) * 72 + mm * 8) = xv[g];

      // A-frag: one contiguous b128 from qt
      bf16x8 afrag = *(const bf16x8*)(qt + mp * 40 + q3 * 8);

      // B-frags: strided u16 reads from xt; 4 c-tiles
      {
        union { bf16x8 v; __hip_bfloat16 h[8]; } b0, b1, b2, b3;
#pragma unroll
        for (int j = 0; j < 8; ++j) {
          const __hip_bfloat16* xr = xt + (q3 * 8 + j) * 72 + mp;
          b0.h[j] = xr[0];
          b1.h[j] = xr[16];
          b2.h[j] = xr[32];
          b3.h[j] = xr[48];
        }
        acc0 = __builtin_amdgcn_mfma_f32_16x16x32_bf16(afrag, b0.v, acc0, 0, 0, 0);
        acc1 = __builtin_amdgcn_mfma_f32_16x16x32_bf16(afrag, b1.v, acc1, 0, 0, 0);
        acc2 = __builtin_amdgcn_mfma_f32_16x16x32_bf16(afrag, b2.v, acc2, 0, 0, 0);
        acc3 = __builtin_amdgcn_mfma_f32_16x16x32_bf16(afrag, b3.v, acc3, 0, 0, 0);
      }

      iv[0] = niv[0]; iv[1] = niv[1]; iv[2] = niv[2]; iv[3] = niv[3];
    }
  }

  // G write: D reg v -> row m=q3*4+v (keep m<8), col mp, tile t
  if (q3 < 2) {
    __hip_bfloat16* Gi = Gbf + (size_t)i * 512;
#pragma unroll
    for (int v = 0; v < 4; ++v) {
      int m = q3 * 4 + v;
      Gi[m * 64 + 0 + mp]  = __float2bfloat16(acc0[v]);
      Gi[m * 64 + 16 + mp] = __float2bfloat16(acc1[v]);
      Gi[m * 64 + 32 + mp] = __float2bfloat16(acc2[v]);
      Gi[m * 64 + 48 + mp] = __float2bfloat16(acc3[v]);
    }
  }

  racc += __shfl_xor(racc, 8);
  racc += __shfl_xor(racc, 16);
  racc += __shfl_xor(racc, 32);
  if (lane < 8) R[(size_t)i * 8 + lane] = racc;
}

// out[N,64] = (Gbf[N,512] @ Wcat[512,64] + R[N,8] @ b[8,64]) / 8 via bf16 MFMA.
__global__ __launch_bounds__(256) void k4_mfma(
    const __hip_bfloat16* __restrict__ Gbf, const float* __restrict__ R,
    const __hip_bfloat16* __restrict__ WtB, const float* __restrict__ bias,
    float* __restrict__ out, int N) {
  __shared__ float4 btile[64 * 65];  // [n][k] bf16, row = 520 bf16 = 65 float4
  {
    const float4* srcp = (const float4*)WtB;  // 4096 float4
    int t = threadIdx.x;
#pragma unroll
    for (int j = 0; j < 16; ++j) {
      int ci = t + j * 256;
      btile[(ci >> 6) * 65 + (ci & 63)] = srcp[ci];
    }
  }
  __syncthreads();

  int wave = threadIdx.x >> 6;
  int lane = threadIdx.x & 63;
  int r0 = (blockIdx.x * 4 + wave) * 16;
  if (r0 >= N) return;

  int m = lane & 15;
  int q = lane >> 4;
  const __bf16* abase = (const __bf16*)(Gbf + (size_t)(r0 + m) * 512) + q * 8;
  const __bf16* lbase = (const __bf16*)btile + (size_t)m * 520 + q * 8;

  f32x4 acc0 = {0, 0, 0, 0}, acc1 = {0, 0, 0, 0};
  f32x4 acc2 = {0, 0, 0, 0}, acc3 = {0, 0, 0, 0};
#pragma unroll
  for (int kt = 0; kt < 16; ++kt) {
    bf16x8 a = *(const bf16x8*)(abase + kt * 32);
    bf16x8 b0 = *(const bf16x8*)(lbase + 0 * 520 + kt * 32);
    bf16x8 b1 = *(const bf16x8*)(lbase + 16 * 520 + kt * 32);
    bf16x8 b2 = *(const bf16x8*)(lbase + 32 * 520 + kt * 32);
    bf16x8 b3 = *(const bf16x8*)(lbase + 48 * 520 + kt * 32);
    acc0 = __builtin_amdgcn_mfma_f32_16x16x32_bf16(a, b0, acc0, 0, 0, 0);
    acc1 = __builtin_amdgcn_mfma_f32_16x16x32_bf16(a, b1, acc1, 0, 0, 0);
    acc2 = __builtin_amdgcn_mfma_f32_16x16x32_bf16(a, b2, acc2, 0, 0, 0);
    acc3 = __builtin_amdgcn_mfma_f32_16x16x32_bf16(a, b3, acc3, 0, 0, 0);
  }

#pragma unroll
  for (int v = 0; v < 4; ++v) {
    int ri = r0 + q * 4 + v;
    if (ri >= N) continue;
    const float* Ri = R + (size_t)ri * 8;
    float b0s = 0, b1s = 0, b2s = 0, b3s = 0;
#pragma unroll
    for (int mm = 0; mm < 8; ++mm) {
      float rv = Ri[mm];
      b0s = fmaf(rv, bias[mm * 64 + 0 + m], b0s);
      b1s = fmaf(rv, bias[mm * 64 + 16 + m], b1s);
      b2s = fmaf(rv, bias[mm * 64 + 32 + m], b2s);
      b3s = fmaf(rv, bias[mm * 64 + 48 + m], b3s);
    }
    float* orow = out + (size_t)ri * 64;
    orow[0 + m]  = (acc0[v] + b0s) * 0.125f;
    orow[16 + m] = (acc1[v] + b1s) * 0.125f;
    orow[32 + m] = (acc2[v] + b2s) * 0.125f;
    orow[48 + m] = (acc3[v] + b3s) * 0.125f;
  }
}

extern "C" void kernel_launch(void* const* d_in, const int* in_sizes, int n_in,
                              void* d_out, int out_size, void* d_ws, size_t ws_size,
                              hipStream_t stream) {
  const float* x  = (const float*)d_in[0];   // [N,64]
  const int* src  = (const int*)d_in[1];     // [E]
  const int* dst  = (const int*)d_in[2];     // [E] sorted
  const float* W  = (const float*)d_in[3];   // [8,64,64] == Wcat[512,64]
  const float* b  = (const float*)d_in[4];   // [8,64]
  const float* Ws = (const float*)d_in[5];   // [64,8]
  const float* bs = (const float*)d_in[6];   // [8]
  const float* Wt = (const float*)d_in[7];   // [64,8]
  const float* bt = (const float*)d_in[8];   // [8]
  int N = in_sizes[0] / CDIM;
  int E = in_sizes[1];
  float* out = (float*)d_out;

  float* ST = (float*)d_ws;                                      // N*16 f32
  __hip_bfloat16* Gbf = (__hip_bfloat16*)(ST + (size_t)N * 16);  // N*512 bf16
  float* R  = (float*)(Gbf + (size_t)N * 512);                   // N*8 f32
  __hip_bfloat16* WtB = (__hip_bfloat16*)(R + (size_t)N * 8);    // 64*512 bf16
  __hip_bfloat16* xbf = WtB + 64 * 512;                          // N*64 bf16
  int* rowptr = (int*)(xbf + (size_t)N * CDIM);                  // N+1 i32

  int nbN = (N + 63) / 64;
  int nbE = (E + 255) / 256;
  k1_pre<<<nbN + 128 + nbE, 256, 0, stream>>>(x, Ws, bs, Wt, bt, W, dst, ST,
                                              xbf, WtB, rowptr, N, E, nbN);
  k3_mfma<<<(N + 3) / 4, 256, 0, stream>>>(xbf, src, rowptr, ST, Gbf, R, N);
  int mtiles = (N + 15) / 16;
  k4_mfma<<<(mtiles + 3) / 4, 256, 0, stream>>>(Gbf, R, WtB, b, out, N);
}